// Round 4
// baseline (518.941 us; speedup 1.0000x reference)
//
#include <hip/hip_runtime.h>

// LIF spiking-neuron forward.
// inputs: (B,C,H,W,T) = (8,64,32,32,100) f32, T innermost (stride 1).
// outputs: syn, mem, spike -- each (B,C,H,W,T) f32, concatenated flat in d_out.
//
// Per pixel, sequential over t:
//   out_t    = (mem - 1 > 0) ? 1 : 0          (uses mem BEFORE update)
//   mem_next = (BETA*mem + syn) * (1 - out)   (uses OLD syn)
//   syn_next = ALPHA*syn + x_t
//
// NUMERICS: f64 recurrence, mul-then-add separated by an asm value barrier
// (no FMA contraction), exact double constants. This exact arithmetic passed
// round 3 with absmax 2.375 (threshold 2.74) -- DO NOT change any FP op.
//
// PERF (round-3 post-mortem): 435us @ 2.3TB/s, occupancy 31%, all pipes idle
// -> latency-bound, LDS-capped at 3 blocks/CU (43KB). This version:
//   * single 21.5KB LDS tile (syn overwrites x in-place; tile reused for
//     mem and spike staging) -> 7 blocks/CU LDS cap
//   * spike bitmask + no rs[] register array -> ~60 VGPR
//   * __launch_bounds__(256,6) -> 24 waves/CU (75% occupancy target)

constexpr int    T_TOT = 100;
constexpr int    TC    = 20;          // timesteps per chunk
constexpr int    NCH   = T_TOT / TC;  // 5 chunks
constexpr int    ROWP  = 21;          // padded row stride; gcd(21,32)=1 -> 2-way (free)
constexpr int    BLOCK = 256;
constexpr int    PPB   = 256;         // pixels per block
constexpr int    V4R   = TC / 4;      // float4s per pixel-chunk = 5
constexpr double ALPHA = 0.95;        // exact Python double
constexpr double BETA  = 0.9;         // exact Python double

// round-to-nearest mul then add in f64, contraction-proof.
__device__ __forceinline__ double mul_add_rn64(double a, double b, double c) {
    double p = a * b;
    asm("" : "+v"(p));
    return p + c;
}

// Coalesced float4 store of the staged tile to one output array.
#define STORE_TILE(OPTR)                                                          \
    do {                                                                          \
        _Pragma("unroll")                                                         \
        for (int k = 0; k < V4R; ++k) {                                           \
            const int idx = tid + k * BLOCK;                                      \
            const int p   = idx / V4R;                                            \
            const int e   = idx - p * V4R;                                        \
            const float* s = &tile[p * ROWP + e * 4];                             \
            float4 v; v.x = s[0]; v.y = s[1]; v.z = s[2]; v.w = s[3];             \
            *reinterpret_cast<float4*>(                                           \
                (OPTR) + (size_t)(pix0 + p) * T_TOT + tbase + e * 4) = v;         \
        }                                                                         \
    } while (0)

__global__ __launch_bounds__(BLOCK, 6)
void lif_fwd(const float* __restrict__ in,
             float* __restrict__ syn_o,
             float* __restrict__ mem_o,
             float* __restrict__ spk_o)
{
    __shared__ float tile[PPB * ROWP];   // 21504 B: x/syn in-place, then mem, then spike

    const int tid  = threadIdx.x;
    const int pix0 = blockIdx.x * PPB;

    double syn = 0.0, mem = 0.0;   // f64 carry (matches round-3 passing arithmetic)
    float rm[TC];                  // mem chunk buffer (statically indexed -> VGPRs)

    for (int c = 0; c < NCH; ++c) {
        const int tbase = c * TC;

        // ---- cooperative load: PPB pixels x TC floats, float4-coalesced ----
        #pragma unroll
        for (int k = 0; k < V4R; ++k) {
            const int idx = tid + k * BLOCK;
            const int p   = idx / V4R;
            const int e   = idx - p * V4R;
            const float4 v = *reinterpret_cast<const float4*>(
                in + (size_t)(pix0 + p) * T_TOT + tbase + e * 4);
            float* d = &tile[p * ROWP + e * 4];
            d[0] = v.x; d[1] = v.y; d[2] = v.z; d[3] = v.w;
        }
        __syncthreads();

        // ---- recurrence (f64); syn overwrites x in row `tid` (thread-local) ----
        unsigned smask = 0u;
        {
            #pragma clang fp contract(off)
            #pragma unroll
            for (int j = 0; j < TC; ++j) {
                const double x     = (double)tile[tid * ROWP + j];
                const bool   o     = (mem - 1.0 > 0.0);
                const double om    = o ? 0.0 : 1.0;              // == (1.0 - out)
                const double mem_n = mul_add_rn64(BETA, mem, syn) * om;
                const double syn_n = mul_add_rn64(ALPHA, syn, x);
                tile[tid * ROWP + j] = (float)syn_n;             // in-place syn
                rm[j]  = (float)mem_n;
                smask |= (o ? 1u : 0u) << j;
                syn = syn_n; mem = mem_n;
            }
        }
        __syncthreads();            // all syn rows written

        STORE_TILE(syn_o);
        __syncthreads();            // syn reads done, rows free

        #pragma unroll
        for (int j = 0; j < TC; ++j) tile[tid * ROWP + j] = rm[j];
        __syncthreads();
        STORE_TILE(mem_o);
        __syncthreads();

        #pragma unroll
        for (int j = 0; j < TC; ++j)
            tile[tid * ROWP + j] = ((smask >> j) & 1u) ? 1.0f : 0.0f;
        __syncthreads();
        STORE_TILE(spk_o);
        __syncthreads();            // spike reads done before next chunk's load
    }
}

extern "C" void kernel_launch(void* const* d_in, const int* in_sizes, int n_in,
                              void* d_out, int out_size, void* d_ws, size_t ws_size,
                              hipStream_t stream) {
    const float* in = (const float*)d_in[0];
    float* out = (float*)d_out;

    const int n    = in_sizes[0];      // B*C*H*W*T = 52,428,800
    const int npix = n / T_TOT;        // 524,288

    float* syn_o = out;
    float* mem_o = out + (size_t)n;
    float* spk_o = out + 2 * (size_t)n;

    dim3 grid(npix / PPB);
    dim3 block(BLOCK);
    lif_fwd<<<grid, block, 0, stream>>>(in, syn_o, mem_o, spk_o);
}